// Round 7
// baseline (161.352 us; speedup 1.0000x reference)
//
#include <hip/hip_runtime.h>
#include <cstdint>
#include <cstddef>

#define NN 4096
#define FDIM 256
#define SPLITK 8

typedef __attribute__((ext_vector_type(4))) float fx4;
typedef __attribute__((ext_vector_type(8))) short s8v;

__device__ inline uint16_t f2bf(float f) {
    union { float f; uint32_t u; } v; v.f = f;
    const uint32_t u = v.u;
    return (uint16_t)((u + 0x7FFFu + ((u >> 16) & 1u)) >> 16);
}

// ---------------- k_h: h = x @ W.T + b  +  adj bit-pack (overlapped) ----------------
// Outputs: gt = bf16(h) transposed [f][j] LINEAR, a1p/a2p partials, bitw = adj
// packed 1 bit/entry (2 MB). The 64 MB adj read rides this VALU-bound GEMM's
// idle memory pipe (R5-measured: stays under the 41 us fill floor).
__global__ __launch_bounds__(512, 4) void k_h(const float* __restrict__ x,
        const float* __restrict__ W, const float* __restrict__ bias,
        const float* __restrict__ att_w, const int* __restrict__ adj,
        uint16_t* __restrict__ gt, uint32_t* __restrict__ bitw,
        float* __restrict__ a1p, float* __restrict__ a2p) {
    __shared__ __align__(16) float xs[2][64 * 68];
    __shared__ __align__(16) float wt[2][64 * 68];
    const int bi = blockIdx.x, bf = blockIdx.y;
    const int t = threadIdx.x;
    const int t256 = t & 255;
    const int kh = t >> 8;                         // K-half: 0 or 1
    const int tx = t256 & 15, ty = t256 >> 4;      // f-group, i-group
    const int pr0 = (bi * 4 + bf) * 16;            // this block's 16 adj rows
    float acc[4][4] = {};
    float rx[8], rw[8];
    #pragma unroll
    for (int u = 0; u < 8; ++u) {
        const int e = t + 512 * u, r = e >> 6, c = e & 63;
        rx[u] = x[(size_t)(bi * 64 + r) * 256 + c];
        rw[u] = W[(size_t)(bf * 64 + r) * 256 + c];
    }
    for (int p = 0; p < 4; ++p) {
        float* xb = xs[p & 1];
        float* wb = wt[p & 1];
        #pragma unroll
        for (int u = 0; u < 8; ++u) {
            const int e = t + 512 * u, r = e >> 6, c = e & 63;
            const int sw = 8 * ((c & 7) ^ ((c >> 3) & 7));
            xb[c * 68 + (r ^ sw)] = rx[u];
            wb[c * 68 + (r ^ sw)] = rw[u];
        }
        __syncthreads();
        if (p < 3) {
            const int kc = (p + 1) * 64;
            #pragma unroll
            for (int u = 0; u < 8; ++u) {
                const int e = t + 512 * u, r = e >> 6, c = e & 63;
                rx[u] = x[(size_t)(bi * 64 + r) * 256 + kc + c];
                rw[u] = W[(size_t)(bf * 64 + r) * 256 + kc + c];
            }
        }
        // ---- adj pack loads for this phase (32 ints -> 1 u32/thread) ----
        const int wi = p * 512 + t;
        const int prow = pr0 + (wi >> 7), pw = wi & 127;
        int4 pa[8];
        {
            const int* ap = adj + (size_t)prow * NN + pw * 32;
            #pragma unroll
            for (int j = 0; j < 8; ++j) pa[j] = *(const int4*)(ap + j * 4);
        }
        #pragma unroll 8
        for (int k = 0; k < 32; ++k) {
            const int kk = kh * 32 + k;
            const int sw = 8 * ((kk & 7) ^ ((kk >> 3) & 7));
            const fx4 av = *(const fx4*)(xb + kk * 68 + ((ty * 4) ^ sw));
            const fx4 bv = *(const fx4*)(wb + kk * 68 + ((tx * 4) ^ sw));
            #pragma unroll
            for (int u = 0; u < 4; ++u)
                #pragma unroll
                for (int v = 0; v < 4; ++v)
                    acc[u][v] += av[u] * bv[v];
        }
        uint32_t bm = 0;
        #pragma unroll
        for (int j = 0; j < 8; ++j) {
            bm |= (uint32_t)(pa[j].x & 1) << (4 * j);
            bm |= (uint32_t)(pa[j].y & 1) << (4 * j + 1);
            bm |= (uint32_t)(pa[j].z & 1) << (4 * j + 2);
            bm |= (uint32_t)(pa[j].w & 1) << (4 * j + 3);
        }
        bitw[(size_t)prow * 128 + pw] = bm;
    }
    __syncthreads();
    float* cbuf = xs[0];
    if (kh == 1) {
        #pragma unroll
        for (int u = 0; u < 4; ++u)
            *(fx4*)(cbuf + t256 * 16 + u * 4) = *(const fx4*)(&acc[u][0]);
    }
    __syncthreads();
    if (kh == 0) {
        float* tileT = wt[0];     // dead after compute: [f_local][j_local] pad 68
        #pragma unroll
        for (int u = 0; u < 4; ++u) {
            const fx4 o = *(const fx4*)(cbuf + t256 * 16 + u * 4);
            #pragma unroll
            for (int v = 0; v < 4; ++v) acc[u][v] += o[v];
        }
        const fx4 bv = *(const fx4*)(bias + bf * 64 + tx * 4);
        const fx4 w1v = *(const fx4*)(att_w + bf * 64 + tx * 4);
        const fx4 w2v = *(const fx4*)(att_w + 256 + bf * 64 + tx * 4);
        #pragma unroll
        for (int u = 0; u < 4; ++u) {
            const int i = bi * 64 + ty * 4 + u;
            fx4 r;
            float s1 = 0.f, s2 = 0.f;
            #pragma unroll
            for (int v = 0; v < 4; ++v) {
                r[v] = acc[u][v] + bv[v];
                s1 += r[v] * w1v[v];
                s2 += r[v] * w2v[v];
            }
            #pragma unroll
            for (int v = 0; v < 4; ++v)
                tileT[(tx * 4 + v) * 68 + ty * 4 + u] = r[v];
            #pragma unroll
            for (int d = 8; d > 0; d >>= 1) {
                s1 += __shfl_down(s1, d, 16);
                s2 += __shfl_down(s2, d, 16);
            }
            if (tx == 0) {
                a1p[bf * NN + i] = s1;
                a2p[bf * NN + i] = s2;
            }
        }
    }
    __syncthreads();
    {   // gt store: all 512 threads, 64 f-rows x 8 col-groups of 8 (linear)
        const float* tileT = wt[0];
        const int fl = t >> 3, cb = t & 7;
        s8v v;
        #pragma unroll
        for (int lo = 0; lo < 8; ++lo)
            v[lo] = (short)f2bf(tileT[fl * 68 + cb * 8 + lo]);
        *(s8v*)(gt + (size_t)(bf * 64 + fl) * NN + bi * 64 + cb * 8) = v;
    }
}

// ---- k_prep: reduce a-partials, max/exp -> E1,E2, Sg=0, edge scan -> wbf ----
__global__ __launch_bounds__(1024) void k_prep(const float* __restrict__ a1p,
        const float* __restrict__ a2p, const int* __restrict__ adj,
        float* __restrict__ E1, float* __restrict__ E2,
        uint16_t* __restrict__ wbf, float* __restrict__ Sg) {
    __shared__ float E1s[NN];
    __shared__ float E2s[NN];
    __shared__ float wraw_s[NN];
    __shared__ float red1[16], red2[16];
    __shared__ int wtot[16];
    __shared__ int base_s;
    const int t = threadIdx.x, lane = t & 63, wv = t >> 6;
    fx4 v1 = {0.f, 0.f, 0.f, 0.f}, v2 = {0.f, 0.f, 0.f, 0.f};
    #pragma unroll
    for (int bf = 0; bf < 4; ++bf) {
        v1 += *(const fx4*)(a1p + bf * NN + t * 4);
        v2 += *(const fx4*)(a2p + bf * NN + t * 4);
    }
    float m1 = fmaxf(fmaxf(v1[0], v1[1]), fmaxf(v1[2], v1[3]));
    float m2 = fmaxf(fmaxf(v2[0], v2[1]), fmaxf(v2[2], v2[3]));
    #pragma unroll
    for (int d = 32; d > 0; d >>= 1) {
        m1 = fmaxf(m1, __shfl_down(m1, d));
        m2 = fmaxf(m2, __shfl_down(m2, d));
    }
    if (lane == 0) { red1[wv] = m1; red2[wv] = m2; }
    __syncthreads();
    if (t == 0) {
        float mm1 = -1e30f, mm2 = -1e30f;
        for (int k = 0; k < 16; ++k) {
            mm1 = fmaxf(mm1, red1[k]);
            mm2 = fmaxf(mm2, red2[k]);
        }
        red1[0] = mm1; red2[0] = mm2;
        *Sg = 0.f;
        base_s = 0;
    }
    __syncthreads();
    const float M1 = red1[0], M2 = red2[0];
    fx4 e1v, e2v, z4 = {0.f, 0.f, 0.f, 0.f};
    #pragma unroll
    for (int j = 0; j < 4; ++j) {
        e1v[j] = expf(v1[j] - M1);
        e2v[j] = expf(v2[j] - M2);
    }
    *(fx4*)(E1s + t * 4) = e1v;
    *(fx4*)(E2s + t * 4) = e2v;
    *(fx4*)(E1 + t * 4) = e1v;
    *(fx4*)(E2 + t * 4) = e2v;
    *(fx4*)(wraw_s + t * 4) = z4;
    __syncthreads();
    for (int row = 0; row < NN; ++row) {
        const int base = base_s;           // uniform
        if (base >= NN) break;             // uniform break
        const int4 a = ((const int4*)(adj + (size_t)row * NN))[t];
        const int vj[4] = {a.x, a.y, a.z, a.w};
        int cnt = 0;
        #pragma unroll
        for (int j = 0; j < 4; ++j) cnt += (vj[j] == 1);
        int inc = cnt;
        #pragma unroll
        for (int d = 1; d < 64; d <<= 1) {
            const int y = __shfl_up(inc, d);
            if (lane >= d) inc += y;
        }
        if (lane == 63) wtot[wv] = inc;
        __syncthreads();                   // B1
        int wbase = 0, total = 0;
        #pragma unroll
        for (int w = 0; w < 16; ++w) {
            const int xw = wtot[w];
            total += xw;
            wbase += (w < wv) ? xw : 0;
        }
        if (t == 0) base_s = base + total;
        int r = base + wbase + inc - cnt;
        if (cnt && r < NN) {
            const float e1 = E1s[row];
            #pragma unroll
            for (int j = 0; j < 4; ++j) {
                if (vj[j] == 1) {
                    if (r < NN) wraw_s[r] = e1 * E2s[t * 4 + j];
                    ++r;
                }
            }
        }
        __syncthreads();                   // B2
    }
    __syncthreads();
    {   // wbf = bf16(wraw) table for k_fused's A-fragment gating
        const fx4 wv4 = *(const fx4*)(wraw_s + t * 4);
        uint2 o;
        o.x = (uint32_t)f2bf(wv4[0]) | ((uint32_t)f2bf(wv4[1]) << 16);
        o.y = (uint32_t)f2bf(wv4[2]) | ((uint32_t)f2bf(wv4[3]) << 16);
        *(uint2*)(wbf + t * 4) = o;
    }
}

// -------- k_fused: part = (bits * wbf) @ gt^T — BARRIER-FREE main loop --------
// R7: no LDS tiles, no __syncthreads, no vmcnt drains. Each wave builds its own
// A-fragments in registers from the bitmask (uint2/row) gated against wbf, and
// loads its wave-private B rows from linear gt. All operands L2-hot. Waves
// free-run; compiler software-pipelines across steps (nothing blocks hoisting).
// S computed exactly (f32) by wave 0 only (it sees the full 64x64 tile's bits).
__global__ __launch_bounds__(256) void k_fused(const uint32_t* __restrict__ bitw,
        const uint16_t* __restrict__ gt, const float* __restrict__ E1,
        const float* __restrict__ E2, const uint16_t* __restrict__ wbf,
        uint16_t* __restrict__ part, float* __restrict__ Sg, int krange) {
    const int ib = blockIdx.x, ks = blockIdx.y;
    const int t = threadIdx.x;
    const int wv = t >> 6, lane = t & 63;
    const int q = lane >> 4, m16 = lane & 15;
    const int i0 = ib * 64, k0 = ks * krange;
    const int ksteps = krange >> 6;
    fx4 acc[4][4];
    #pragma unroll
    for (int a = 0; a < 4; ++a)
        #pragma unroll
        for (int b2 = 0; b2 < 4; ++b2) acc[a][b2] = (fx4){0.f, 0.f, 0.f, 0.f};
    float sS = 0.f;
    float e1r[4];
    #pragma unroll
    for (int p = 0; p < 4; ++p) e1r[p] = E1[i0 + p * 16 + m16];
    // wave-private B row pointers (q*8 folded): B[k][f] = gt[f][k]
    const uint16_t* rowp[4];
    #pragma unroll
    for (int ft = 0; ft < 4; ++ft)
        rowp[ft] = gt + (size_t)(wv * 64 + ft * 16 + m16) * NN + q * 8;
    // per-lane bit-row pointers: rows it*16+m16, window base k0
    const uint32_t* bp[4];
    #pragma unroll
    for (int it = 0; it < 4; ++it)
        bp[it] = bitw + (size_t)(i0 + it * 16 + m16) * 128 + (k0 >> 5);

    for (int stp = 0; stp < ksteps; ++stp) {
        const int kk = k0 + stp * 64;
        // ---- loads (all L2-hot, no ordering constraints) ----
        uint2 bw[4];
        #pragma unroll
        for (int it = 0; it < 4; ++it) bw[it] = *(const uint2*)(bp[it] + stp * 2);
        uint4 wp[2];
        #pragma unroll
        for (int khh = 0; khh < 2; ++khh)
            wp[khh] = *(const uint4*)(wbf + kk + khh * 32 + q * 8);
        s8v B[4][2];
        #pragma unroll
        for (int ft = 0; ft < 4; ++ft)
            #pragma unroll
            for (int khh = 0; khh < 2; ++khh)
                B[ft][khh] = *(const s8v*)(rowp[ft] + kk + khh * 32);
        // ---- A-fragment build (registers) + MFMA ----
        #pragma unroll
        for (int it = 0; it < 4; ++it) {
            #pragma unroll
            for (int khh = 0; khh < 2; ++khh) {
                const uint32_t b8 = ((khh ? bw[it].y : bw[it].x) >> (q * 8)) & 0xFFu;
                union { uint32_t w[4]; s8v v; } af;
                const uint32_t* wpw = (const uint32_t*)&wp[khh];
                #pragma unroll
                for (int n = 0; n < 4; ++n) {
                    const uint32_t msk = ((b8 >> (2 * n)) & 1u ? 0xFFFFu : 0u) |
                                         ((b8 >> (2 * n + 1)) & 1u ? 0xFFFF0000u : 0u);
                    af.w[n] = wpw[n] & msk;
                }
                #pragma unroll
                for (int ft = 0; ft < 4; ++ft)
                    acc[it][ft] = __builtin_amdgcn_mfma_f32_16x16x32_bf16(
                        af.v, B[ft][khh], acc[it][ft], 0, 0, 0);
            }
        }
        // ---- exact S (wave 0 only: its (it,m16,q,kh) lanes tile 64x64 once) ----
        if (wv == 0) {
            #pragma unroll
            for (int khh = 0; khh < 2; ++khh) {
                const fx4 e2a = *(const fx4*)(E2 + kk + khh * 32 + q * 8);
                const fx4 e2b = *(const fx4*)(E2 + kk + khh * 32 + q * 8 + 4);
                #pragma unroll
                for (int it = 0; it < 4; ++it) {
                    const uint32_t b8 = ((khh ? bw[it].y : bw[it].x) >> (q * 8)) & 0xFFu;
                    float s8 = 0.f;
                    #pragma unroll
                    for (int j = 0; j < 4; ++j) {
                        s8 += ((b8 >> j) & 1u) ? e2a[j] : 0.f;
                        s8 += ((b8 >> (j + 4)) & 1u) ? e2b[j] : 0.f;
                    }
                    sS += e1r[it] * s8;
                }
            }
        }
    }
    if (wv == 0) {
        #pragma unroll
        for (int d = 32; d > 0; d >>= 1) sS += __shfl_down(sS, d);
        if (lane == 0) atomicAdd(Sg, sS);
    }
    // bf16 partials; C/D layout: col=lane&15, row=(lane>>4)*4+reg
    uint16_t* dst = part + (size_t)ks * NN * FDIM;
    #pragma unroll
    for (int it = 0; it < 4; ++it) {
        #pragma unroll
        for (int ft = 0; ft < 4; ++ft) {
            const int f = wv * 64 + ft * 16 + m16;
            #pragma unroll
            for (int r = 0; r < 4; ++r) {
                const int i = i0 + it * 16 + q * 4 + r;
                dst[(size_t)i * FDIM + f] = f2bf(acc[it][ft][r]);
            }
        }
    }
}

// -------- k_out: out = relu(sum_k part_k) / S (bf16 partials, 8 f/thread) --------
__global__ __launch_bounds__(256) void k_out(const uint16_t* __restrict__ part,
        const float* __restrict__ Sg, float* __restrict__ out, int nsplit) {
    const size_t idx = ((size_t)blockIdx.x * 256 + threadIdx.x) * 8;
    const float inv = 1.0f / (*Sg);
    float s[8] = {};
    for (int k = 0; k < nsplit; ++k) {
        const s8v v = *(const s8v*)(part + (size_t)k * NN * FDIM + idx);
        #pragma unroll
        for (int j = 0; j < 8; ++j) {
            union { uint32_t u; float f; } cv;
            cv.u = ((uint32_t)(uint16_t)v[j]) << 16;
            s[j] += cv.f;
        }
    }
    fx4 r0, r1;
    #pragma unroll
    for (int j = 0; j < 4; ++j) {
        r0[j] = fmaxf(s[j], 0.f) * inv;
        r1[j] = fmaxf(s[4 + j], 0.f) * inv;
    }
    *(fx4*)(out + idx) = r0;
    *(fx4*)(out + idx + 4) = r1;
}

extern "C" void kernel_launch(void* const* d_in, const int* in_sizes, int n_in,
                              void* d_out, int out_size, void* d_ws, size_t ws_size,
                              hipStream_t stream) {
    const float* x     = (const float*)d_in[0];
    const int*   adj   = (const int*)d_in[1];
    const float* W     = (const float*)d_in[2];
    const float* bias  = (const float*)d_in[3];
    const float* att_w = (const float*)d_in[4];
    // att_b (d_in[5]) cancels exactly in the softmax — unused.
    float* out = (float*)d_out;
    char* ws = (char*)d_ws;
    uint16_t* gt   = (uint16_t*)(ws + 0);            // 2 MB: bf16(h) transposed
    uint32_t* bitw = (uint32_t*)(ws + 2097152);      // 2 MB: adj bitmask
    float*    a1p  = (float*)(ws + 4194304);         // 64 KB (4 x 4096)
    float*    a2p  = (float*)(ws + 4259840);         // 64 KB
    float*    E1   = (float*)(ws + 4325376);         // 16 KB
    float*    E2   = (float*)(ws + 4341760);         // 16 KB
    uint16_t* wbf  = (uint16_t*)(ws + 4358144);      // 8 KB: bf16(wraw)
    float*    Sg   = (float*)(ws + 4366336);         // 256 B
    uint16_t* part = (uint16_t*)(ws + 4366592);      // splitk x 2 MB (bf16)
    (void)in_sizes; (void)n_in; (void)out_size;

    const size_t avail = (ws_size > 4366592) ? (ws_size - 4366592) : 0;
    int splitk = 1;
    while (splitk < 8 &&
           (size_t)(splitk * 2) * NN * FDIM * sizeof(uint16_t) <= avail)
        splitk <<= 1;
    const int krange = NN / splitk;

    k_h    <<<dim3(64, 4), 512, 0, stream>>>(x, W, bias, att_w, adj, gt, bitw, a1p, a2p);
    k_prep <<<dim3(1), 1024, 0, stream>>>(a1p, a2p, adj, E1, E2, wbf, Sg);
    k_fused<<<dim3(64, splitk), 256, 0, stream>>>(bitw, gt, E1, E2, wbf, part, Sg, krange);
    k_out  <<<dim3(512), 256, 0, stream>>>(part, Sg, out, splitk);
}